// Round 5
// baseline (123.194 us; speedup 1.0000x reference)
//
#include <hip/hip_runtime.h>

#define NS 1024      // N samples
#define MM 64        // M patches
#define CC 4         // C compartments
#define NSTEPS 100
#define CLIPMAX 1e10f

// Broadcast lane k's value to all lanes (k may be a uniform/SGPR value).
__device__ __forceinline__ float rdlane(float v, int k) {
    return __uint_as_float(__builtin_amdgcn_readlane(__float_as_uint(v), k));
}

// 4 waves per sample (256 threads), all lanes active in every wave.
// Wave w owns j,k in [w*16, w*16+16):
//   Gcol[jj] = beta*Rt[n, lane, w*16+jj]/ntot[..]   (phase A partial product)
//   Rrow[kk] = R[n, lane, w*16+kk]                  (phase B partial matvec)
// Cross-wave combine via tiny LDS [4][64] arrays (conflict-free); each wave
// redundantly reconstructs p[i]/s[j]/rho so phase B uses intra-wave readlane.
// 4096 waves = 4/SIMD -> latency hiding that r2-r4 (1 wave/SIMD) never had.
__global__ __launch_bounds__(256, 4) void metapop_kernel(
    const float* __restrict__ R,     // (NS, MM, MM)
    const float* __restrict__ T,     // (NS, CC, CC)
    const float* __restrict__ rho0,  // (NS, MM, CC)
    const float* __restrict__ beta,  // (NS,)
    float* __restrict__ out)         // (NSTEPS, NS, MM, CC)
{
    const int n    = blockIdx.x;
    const int t    = threadIdx.x;
    const int lane = t & 63;
    const int w    = t >> 6;       // wave id 0..3
    const int base = w * 16;

    __shared__ float ppart[4][MM];   // phase A partial products
    __shared__ float sp[4][MM];      // phase B partial sums

    const float* Rn = R + (size_t)n * (MM * MM);

    // ---- Rrow: this wave's 16 columns of row `lane` (4x float4) ----
    float Rrow[16];
    {
        const float4* p4 = (const float4*)(Rn + lane * MM + base);
        #pragma unroll
        for (int q = 0; q < 4; ++q) {
            float4 v = p4[q];
            Rrow[4*q+0] = v.x; Rrow[4*q+1] = v.y;
            Rrow[4*q+2] = v.z; Rrow[4*q+3] = v.w;
        }
    }

    // ---- ntot: column sums, split 4-ways over rows ----
    {
        float s = 0.f;
        #pragma unroll
        for (int ii = 0; ii < 16; ++ii) s += Rn[(base + ii) * MM + lane];
        ppart[w][lane] = s;
    }
    __syncthreads();
    float binv;   // lane j holds beta/ntot[j]  (identical in all waves)
    binv = beta[n] / (ppart[0][lane] + ppart[1][lane]
                    + ppart[2][lane] + ppart[3][lane]);
    __syncthreads();   // ppart free for reuse

    // ---- Gcol: this wave's 16 j's of the transposed-gather matrix ----
    // Rt[n,i,j] = R[(i&15)*64+j, (n&15)*4+(i>>4), n>>4]
    float Gcol[16];
    {
        const int q     = n >> 4;
        const int a     = ((n & 15) << 2) + (lane >> 4);
        const int sbase = (lane & 15) << 6;
        #pragma unroll
        for (int jj = 0; jj < 16; ++jj) {
            int j = base + jj;
            float v = R[(size_t)(sbase + j) * (MM * MM) + a * MM + q];
            Gcol[jj] = v * rdlane(binv, j);
        }
    }

    // ---- T[n] (uniform) and rho0 (duplicated in all 4 waves) ----
    float tt[CC][CC];
    {
        const float* Tn = T + n * (CC * CC);
        #pragma unroll
        for (int k = 0; k < CC; ++k)
            #pragma unroll
            for (int l = 0; l < CC; ++l)
                tt[k][l] = Tn[k * CC + l];
    }
    float rh[CC];
    {
        float4 v = *(const float4*)(rho0 + (size_t)n * (MM * CC) + lane * CC);
        rh[0] = v.x; rh[1] = v.y; rh[2] = v.z; rh[3] = v.w;
    }

    float* ob = out + (size_t)n * (MM * CC) + lane * CC;
    const size_t stride = (size_t)NS * MM * CC;

    for (int step = 0; step < NSTEPS; ++step) {
        // trajectory records PRE-update state; wave 0 stores (coalesced float4)
        if (w == 0)
            *(float4*)(ob + (size_t)step * stride) =
                make_float4(rh[0], rh[1], rh[2], rh[3]);

        // phase A partial (lane = i): prod over this wave's 16 j's, 2 chains
        const float r1 = rh[1];
        float pr0 = 1.f, pr1 = 1.f;
        #pragma unroll
        for (int jj = 0; jj < 8; ++jj) {
            pr0 *= 1.f - r1 * Gcol[jj];
            pr1 *= 1.f - r1 * Gcol[jj + 8];
        }
        ppart[w][lane] = pr0 * pr1;
        __syncthreads();   // barrier 1

        // p[i] reconstructed per-lane in EVERY wave (so phase B readlane is
        // intra-wave); identical arithmetic -> bit-identical across waves
        const float p = 1.f - (ppart[0][lane] * ppart[1][lane])
                            * (ppart[2][lane] * ppart[3][lane]);

        // phase B partial (lane = j): sum over this wave's 16 k's, 2 chains
        float s0 = 0.f, s1 = 0.f;
        #pragma unroll
        for (int kk = 0; kk < 8; ++kk) {
            s0 += Rrow[kk]     * rdlane(p, base + kk);
            s1 += Rrow[kk + 8] * rdlane(p, base + kk + 8);
        }
        sp[w][lane] = s0 + s1;
        __syncthreads();   // barrier 2

        const float ssum = (sp[0][lane] + sp[1][lane])
                         + (sp[2][lane] + sp[3][lane]);
        const float sr   = (rh[0] + rh[1]) + (rh[2] + rh[3]);
        const float ninf = (1.f - sr) * ssum;

        // phase C (lane-local, duplicated in all waves -> rho stays in regs)
        float nr[CC];
        #pragma unroll
        for (int l = 0; l < CC; ++l) {
            float v = rh[0] * tt[0][l] + rh[1] * tt[1][l]
                    + rh[2] * tt[2][l] + rh[3] * tt[3][l];
            if (l == 0) v += ninf;
            nr[l] = fminf(fmaxf(v, 0.f), CLIPMAX);
        }
        #pragma unroll
        for (int l = 0; l < CC; ++l) rh[l] = nr[l];
    }
}

extern "C" void kernel_launch(void* const* d_in, const int* in_sizes, int n_in,
                              void* d_out, int out_size, void* d_ws, size_t ws_size,
                              hipStream_t stream) {
    const float* R    = (const float*)d_in[0];
    const float* T    = (const float*)d_in[1];
    const float* rho0 = (const float*)d_in[2];
    const float* beta = (const float*)d_in[3];
    float* out = (float*)d_out;
    hipLaunchKernelGGL(metapop_kernel, dim3(NS), dim3(256), 0, stream,
                       R, T, rho0, beta, out);
}